// Round 3
// baseline (819.702 us; speedup 1.0000x reference)
//
#include <hip/hip_runtime.h>

typedef short short8 __attribute__((ext_vector_type(8)));
typedef float floatx16 __attribute__((ext_vector_type(16)));
typedef unsigned short u16;

#define BATCH 256
#define FEAT 768
#define NBALLS 1500
#define NCLS 150
#define NTRI 294528
#define SN 1504          // padded column stride of S
#define NCOL 320         // 256 ood cols + 64 batch slots
#define NSLICE 12        // 12 x 64-row slices of the 768 output rows
#define BETA_C 0.1f

__device__ __forceinline__ u16 f2bf(float f) {
    unsigned u = __float_as_uint(f);
    return (u16)((u + 0x7FFFu + ((u >> 16) & 1u)) >> 16);
}
__device__ __forceinline__ unsigned pack2bf(float lo, float hi) {
    unsigned ul = __float_as_uint(lo); ul = (ul + 0x7FFFu + ((ul >> 16) & 1u)) >> 16;
    unsigned uh = __float_as_uint(hi); uh = (uh + 0x7FFFu + ((uh >> 16) & 1u)) & 0xFFFF0000u;
    return uh | ul;
}
__device__ __forceinline__ unsigned bf16sub2(unsigned a, unsigned b) {
    float lo = __uint_as_float(a << 16) - __uint_as_float(b << 16);
    float hi = __uint_as_float(a & 0xFFFF0000u) - __uint_as_float(b & 0xFFFF0000u);
    unsigned ul = __float_as_uint(lo); ul = (ul + 0x7FFFu + ((ul >> 16) & 1u)) >> 16;
    unsigned uh = __float_as_uint(hi); uh = (uh + 0x7FFFu + ((uh >> 16) & 1u)) & 0xFFFF0000u;
    return uh | ul;
}
__device__ __forceinline__ unsigned trioff(int x) {      // x*(x-1)/2
    return ((unsigned)x * (unsigned)(x - 1)) >> 1;
}

// ---------------- fused prep: bf16 conversion + centroid norms + class lists + zeroing ----
__global__ __launch_bounds__(256) void k_prep(
    const float* __restrict__ pooled, const float* __restrict__ ood,
    const float* __restrict__ cent, const int* __restrict__ ball_labels,
    u16* __restrict__ xsrc, u16* __restrict__ cent_bf, float* __restrict__ cnorm,
    int* __restrict__ cls_cnt, int* __restrict__ cls_list,
    float* __restrict__ euc2_main, int* __restrict__ bcount) {
    __shared__ int scnt;
    const int t = threadIdx.x, blk = blockIdx.x;
    const int tid = blk * 256 + t, stride = gridDim.x * 256;
    uint2* xp = (uint2*)xsrc;                       // pooled -> rows 0..255
    for (int i = tid; i < (BATCH * FEAT) / 4; i += stride) {
        const float4 v = ((const float4*)pooled)[i];
        xp[i] = make_uint2(pack2bf(v.x, v.y), pack2bf(v.z, v.w));
    }
    uint2* xo = (uint2*)(xsrc + BATCH * FEAT);      // ood -> rows 256..511
    for (int i = tid; i < (BATCH * FEAT) / 4; i += stride) {
        const float4 v = ((const float4*)ood)[i];
        xo[i] = make_uint2(pack2bf(v.x, v.y), pack2bf(v.z, v.w));
    }
    uint2* cd = (uint2*)cent_bf;
    for (int i = tid; i < (NBALLS * FEAT) / 4; i += stride) {
        const float4 v = ((const float4*)cent)[i];
        cd[i] = make_uint2(pack2bf(v.x, v.y), pack2bf(v.z, v.w));
    }
    for (int i = tid; i < BATCH; i += stride) euc2_main[i] = 0.f;
    for (int i = tid; i < NCLS; i += stride) bcount[i] = 0;

    if (blk >= 512 && blk < 512 + 375) {            // centroid squared norms, 4 waves/block
        int cid = (blk - 512) * 4 + (t >> 6);
        int lane = t & 63;
        const float* row = cent + (size_t)cid * FEAT;
        float s = 0.f;
#pragma unroll
        for (int q = 0; q < FEAT / 64; ++q) { float v = row[lane + q * 64]; s += v * v; }
        for (int o = 32; o > 0; o >>= 1) s += __shfl_down(s, o);
        if (lane == 0) cnorm[cid] = s;
    }
    if (blk >= 887 && blk < 887 + NCLS) {           // per-class ball lists
        int k = blk - 887;
        if (t == 0) scnt = 0;
        __syncthreads();
        for (int n = t; n < NBALLS; n += 256) {
            if (ball_labels[n] == k) {
                int p = atomicAdd(&scnt, 1);
                if (p < 32) cls_list[k * 32 + p] = n;
            }
        }
        __syncthreads();
        if (t == 0) cls_cnt[k] = scnt < 32 ? scnt : 32;
    }
}

// ---------------- S[r][n] = ||c_n||^2 - 2 q_r . c_n (monotone distance surrogate) --------
__global__ __launch_bounds__(256) void k_gemm_s(
    const u16* __restrict__ xsrc, const u16* __restrict__ cent_bf,
    const float* __restrict__ cnorm, float* __restrict__ S) {
    __shared__ u16 Aq[64 * 40];
    __shared__ u16 Bc[128 * 40];
    const int t = threadIdx.x;
    const int r0 = blockIdx.x * 64;
    const int n0 = blockIdx.y * 128;
    const int w = t >> 6, lane = t & 63;
    const int ml = lane & 31, kh = lane >> 5;
    const int rt = w & 1, cg = w >> 1;

    floatx16 acc[2];
#pragma unroll
    for (int ct = 0; ct < 2; ++ct)
#pragma unroll
        for (int e = 0; e < 16; ++e) acc[ct][e] = 0.f;

    const int ar = t >> 2, aj = (t & 3) * 8;
    const u16* asrc = xsrc + (size_t)(r0 + ar) * FEAT;
    const int bcn = t >> 1, bj = (t & 1) * 16;
    const int ng = n0 + bcn;
    const u16* bsrc = cent_bf + (size_t)(ng < NBALLS ? ng : 0) * FEAT;
    const bool bvalid = (ng < NBALLS);

#pragma unroll 1
    for (int k0 = 0; k0 < FEAT; k0 += 32) {
        uint4 av = *(const uint4*)(asrc + k0 + aj);
        uint4 b0, b1;
        if (bvalid) {
            b0 = *(const uint4*)(bsrc + k0 + bj);
            b1 = *(const uint4*)(bsrc + k0 + bj + 8);
        } else { b0 = make_uint4(0,0,0,0); b1 = make_uint4(0,0,0,0); }
        *(uint4*)&Aq[ar * 40 + aj] = av;
        *(uint4*)&Bc[bcn * 40 + bj] = b0;
        *(uint4*)&Bc[bcn * 40 + bj + 8] = b1;
        __syncthreads();
#pragma unroll
        for (int ks = 0; ks < 2; ++ks) {
            short8 a = *(const short8*)&Aq[(rt * 32 + ml) * 40 + ks * 16 + kh * 8];
#pragma unroll
            for (int ct = 0; ct < 2; ++ct) {
                short8 b = *(const short8*)&Bc[((cg * 2 + ct) * 32 + ml) * 40 + ks * 16 + kh * 8];
                acc[ct] = __builtin_amdgcn_mfma_f32_32x32x16_bf16(a, b, acc[ct], 0, 0, 0);
            }
        }
        __syncthreads();
    }
#pragma unroll
    for (int ct = 0; ct < 2; ++ct) {
        int colg = n0 + (cg * 2 + ct) * 32 + ml;
        if (colg >= SN) continue;
        float cn = (colg < NBALLS) ? cnorm[colg] : 0.f;
#pragma unroll
        for (int reg = 0; reg < 16; ++reg) {
            int row = (reg & 3) + 8 * (reg >> 2) + 4 * kh;
            int rgl = r0 + rt * 32 + row;
            S[(size_t)rgl * SN + colg] = cn - 2.f * acc[ct][reg];
        }
    }
}

// ---------------- fused argmins: block 0 = main branch, blocks 1..150 = ood classes ------
__global__ void k_argmin(const float* __restrict__ S, const int* __restrict__ labels,
                         const int* __restrict__ cls_cnt, const int* __restrict__ cls_list,
                         int* __restrict__ ball_ids, int* __restrict__ bcount,
                         int* __restrict__ blist, int* __restrict__ nearidx) {
    const int t = threadIdx.x;
    if (blockIdx.x == 0) {
        int k = labels[t];
        if (k < 0) k = 0; if (k >= NCLS) k = NCLS - 1;
        int cnt = cls_cnt[k];
        float best = 3.4e38f; int bestn = 0;
        for (int i = 0; i < cnt; ++i) {
            int n = cls_list[k * 32 + i];
            float v = S[(size_t)t * SN + n];
            if (v < best) { best = v; bestn = n; }
        }
        ball_ids[t] = bestn;
        int slot = atomicAdd(&bcount[k], 1);
        if (slot < 64) blist[k * 64 + slot] = t;
    } else {
        int k = blockIdx.x - 1;
        int cnt = cls_cnt[k];
        float best = 3.4e38f; int bestn = 0;
        for (int i = 0; i < cnt; ++i) {
            int n = cls_list[k * 32 + i];
            float v = S[(size_t)(BATCH + t) * SN + n];
            if (v < best) { best = v; bestn = n; }
        }
        nearidx[k * BATCH + t] = bestn;
    }
}

// ---------------- THE big kernel: fused R-build + per-class GEMM + column norms ----------
// K-step 64, XOR-swizzled LDS (conflict-free), double-buffered A regs, 3 blocks/CU.
// LDS element (row, k): chunk=k/8, pos=k%8 -> idx = row*64 + ((chunk^(row&7))*8) + pos
__global__ __launch_bounds__(256, 3) void k_gemm2(
    const float* __restrict__ Lp, const float* __restrict__ Up, const float* __restrict__ Ddp,
    const u16* __restrict__ xsrc, const u16* __restrict__ cent_bf,
    const int* __restrict__ nearidx, const int* __restrict__ bcount,
    const int* __restrict__ blist, const int* __restrict__ ball_ids,
    float* __restrict__ euc2_part) {
    __shared__ u16 At[64 * 64];          // 8 KB
    __shared__ u16 Bt[NCOL * 64];        // 40 KB (aliased as sred after the K loop)
    __shared__ unsigned oidx_s[NCOL];
    __shared__ unsigned cidx_s[NCOL];

    const int t = threadIdx.x;
    const int slice = blockIdx.x;
    const int i0 = slice * 64;
    const int k = blockIdx.y;
    const float* __restrict__ Lr = Lp + (size_t)k * NTRI;
    const float* __restrict__ Ur = Up + (size_t)k * NTRI;
    const float* __restrict__ Ddr = Ddp + (size_t)k * FEAT;

    const int w = t >> 6, lane = t & 63;
    const int ml = lane & 31, kh = lane >> 5;
    const int rt = w & 1, cg = w >> 1;

    float aL[2][16];
    // A tile load: 64 rows x 64 k of R_k -> 16 fp32/thread, three uniform variants
    auto loadA = [&](int j0, int buf) {
        if (j0 + 64 <= i0) {                         // pure lower: rows of L, contiguous
#pragma unroll
            for (int u = 0; u < 2; ++u) {
                const int g = u * 256 + t;
                const int row = g >> 3, chunk = g & 7;
                const float* p = Lr + trioff(i0 + row) + j0 + chunk * 8;
#pragma unroll
                for (int e = 0; e < 8; ++e) aL[buf][u * 8 + e] = p[e];
            }
        } else if (j0 >= i0 + 64) {                  // pure upper: columns of U (contig in i)
#pragma unroll
            for (int v = 0; v < 2; ++v) {
                const int jj = (t >> 3) + 32 * v;
                const float* p = Ur + trioff(j0 + jj) + i0 + (t & 7);
#pragma unroll
                for (int e = 0; e < 8; ++e) aL[buf][v * 8 + e] = p[8 * e];
            }
        } else {                                     // diagonal tile (j0 == i0)
#pragma unroll
            for (int u = 0; u < 16; ++u) {
                const int idx = u * 256 + t;
                const int row = idx >> 6, col = idx & 63;
                const int i = i0 + row, jg = j0 + col;
                float v;
                if (i > jg)      v = Lr[trioff(i) + jg];
                else if (i < jg) v = Ur[trioff(jg) + i];
                else             v = Ddr[i];
                aL[buf][u] = v;
            }
        }
    };
    auto storeA = [&](int j0, int buf) {
        if (j0 + 64 <= i0) {
#pragma unroll
            for (int u = 0; u < 2; ++u) {
                const int g = u * 256 + t;
                const int row = g >> 3, chunk = g & 7;
                uint4 rv;
                rv.x = pack2bf(aL[buf][u*8+0], aL[buf][u*8+1]);
                rv.y = pack2bf(aL[buf][u*8+2], aL[buf][u*8+3]);
                rv.z = pack2bf(aL[buf][u*8+4], aL[buf][u*8+5]);
                rv.w = pack2bf(aL[buf][u*8+6], aL[buf][u*8+7]);
                *(uint4*)&At[row * 64 + ((chunk ^ (row & 7)) * 8)] = rv;
            }
        } else if (j0 >= i0 + 64) {
#pragma unroll
            for (int v = 0; v < 2; ++v) {
                const int jj = (t >> 3) + 32 * v;
                const int chunk = jj >> 3, pos = jj & 7;
#pragma unroll
                for (int e = 0; e < 8; ++e) {
                    const int row = (t & 7) + 8 * e;
                    At[row * 64 + ((chunk ^ (row & 7)) * 8) + pos] = f2bf(aL[buf][v * 8 + e]);
                }
            }
        } else {
#pragma unroll
            for (int u = 0; u < 16; ++u) {
                const int idx = u * 256 + t;
                const int row = idx >> 6, col = idx & 63;
                At[row * 64 + (((col >> 3) ^ (row & 7)) * 8) + (col & 7)] = f2bf(aL[buf][u]);
            }
        }
    };
    auto stageB = [&](int j0) {                      // 320 cols x 64 k, bf16 subtract
#pragma unroll
        for (int u = 0; u < 10; ++u) {
            const int g = u * 256 + t;
            const int col = g >> 3, chunk = g & 7;
            const unsigned ci = cidx_s[col];
            u16* dst = &Bt[col * 64 + ((chunk ^ (col & 7)) * 8)];
            if (ci == 0xFFFFFFFFu) {
                *(uint4*)dst = make_uint4(0u, 0u, 0u, 0u);
            } else {
                const u16* o = xsrc + (size_t)oidx_s[col] * FEAT + j0 + chunk * 8;
                const u16* c = cent_bf + (size_t)ci * FEAT + j0 + chunk * 8;
                const uint4 ov = *(const uint4*)o;
                const uint4 cv = *(const uint4*)c;
                uint4 rv;
                rv.x = bf16sub2(ov.x, cv.x); rv.y = bf16sub2(ov.y, cv.y);
                rv.z = bf16sub2(ov.z, cv.z); rv.w = bf16sub2(ov.w, cv.w);
                *(uint4*)dst = rv;
            }
        }
    };

    loadA(0, 0);                                     // issue first A loads ASAP

    int bc = bcount[k]; if (bc > 64) bc = 64;
    oidx_s[t] = 256u + (unsigned)t;                  // ood rows live at xsrc rows 256..511
    cidx_s[t] = (unsigned)nearidx[k * BATCH + t];
    if (t < 64) {
        unsigned oi = 0u, ci = 0xFFFFFFFFu;
        if (t < bc) { int b = blist[k * 64 + t]; oi = (unsigned)b; ci = (unsigned)ball_ids[b]; }
        oidx_s[256 + t] = oi;
        cidx_s[256 + t] = ci;
    }
    __syncthreads();

    floatx16 acc[5];
#pragma unroll
    for (int cc = 0; cc < 5; ++cc)
#pragma unroll
        for (int e = 0; e < 16; ++e) acc[cc][e] = 0.f;

#pragma unroll 1
    for (int it = 0; it < FEAT / 64; ++it) {
        const int j0 = it * 64;
        const int buf = it & 1;
        if (it + 1 < FEAT / 64) loadA(j0 + 64, buf ^ 1);  // overlap storeA+stageB below
        storeA(j0, buf);
        stageB(j0);
        __syncthreads();
#pragma unroll
        for (int ks = 0; ks < 4; ++ks) {
            const int ch = ks * 2 + kh;
            const int arow = rt * 32 + ml;
            const short8 af = *(const short8*)&At[arow * 64 + ((ch ^ (arow & 7)) * 8)];
#pragma unroll
            for (int cc = 0; cc < 5; ++cc) {
                const int brow = (cg * 5 + cc) * 32 + ml;
                const short8 bv = *(const short8*)&Bt[brow * 64 + ((ch ^ (brow & 7)) * 8)];
                acc[cc] = __builtin_amdgcn_mfma_f32_32x32x16_bf16(af, bv, acc[cc], 0, 0, 0);
            }
        }
        __syncthreads();
    }

    // per-column sum of squares over this 64-row slice; combine row-halves via LDS (alias Bt)
    float* sred = (float*)Bt;
#pragma unroll
    for (int cc = 0; cc < 5; ++cc) {
        float s = 0.f;
#pragma unroll
        for (int e = 0; e < 16; ++e) { float v = acc[cc][e]; s += v * v; }
        s += __shfl_xor(s, 32);
        if (kh == 0) sred[rt * NCOL + cg * 160 + cc * 32 + ml] = s;
    }
    __syncthreads();
    float* outp = euc2_part + ((size_t)k * NSLICE + slice) * NCOL;
    outp[t] = sred[t] + sred[NCOL + t];
    if (t < 64) outp[256 + t] = sred[256 + t] + sred[NCOL + 256 + t];
}

// ---------------- slice reduction: 12 partials -> euc2 ----------------
__global__ void k_reduce(const float* __restrict__ euc2_part, const int* __restrict__ bcount,
                         const int* __restrict__ blist,
                         float* __restrict__ euc2_ood, float* __restrict__ euc2_main) {
    const int k = blockIdx.x, t = threadIdx.x;
    const float* p = euc2_part + (size_t)k * NSLICE * NCOL;
    float s = 0.f;
#pragma unroll
    for (int s12 = 0; s12 < NSLICE; ++s12) s += p[s12 * NCOL + t];
    euc2_ood[k * BATCH + t] = s;
    if (t < 64) {
        int bc = bcount[k]; if (bc > 64) bc = 64;
        if (t < bc) {
            float s2 = 0.f;
#pragma unroll
            for (int s12 = 0; s12 < NSLICE; ++s12) s2 += p[s12 * NCOL + 256 + t];
            euc2_main[blist[k * 64 + t]] = s2;
        }
    }
}

// ---------------- final loss assembly ----------------
__global__ void k_final(const float* __restrict__ euc2_main, const float* __restrict__ euc2_ood,
                        const int* __restrict__ ball_ids, const int* __restrict__ nearidx,
                        const float* __restrict__ delta, float* __restrict__ out) {
    __shared__ float red[256];
    const int t = threadIdx.x;

    float euc = sqrtf(euc2_main[t]);
    float d = delta[ball_ids[t]];
    float pl = (d > euc) ? expf(euc - d) : (euc - d);
    float pn = (euc > d) ? 1.f : 0.f;
    float nn = (euc < d) ? 1.f : 0.f;

    float s = 0.f;
    for (int k = 0; k < NCLS; ++k) {
        int idx = k * BATCH + t;
        float e = sqrtf(euc2_ood[idx]);
        float dn = delta[nearidx[idx]];
        s += (dn > e) ? (dn - e + BETA_C) : (BETA_C * expf(dn - e));
    }

    auto reduce = [&](float v) -> float {
        red[t] = v; __syncthreads();
        for (int o = 128; o > 0; o >>= 1) {
            if (t < o) red[t] += red[t + o];
            __syncthreads();
        }
        float r = red[0]; __syncthreads();
        return r;
    };
    float pos_sum = reduce(pl);
    float pnum    = reduce(pn);
    float nnum    = reduce(nn);
    float neg_sum = reduce(s);
    if (t == 0) {
        float pos_mean = pos_sum / (float)BATCH;
        float neg_mean = neg_sum / (float)BATCH;
        out[0] = pos_mean;
        out[1] = neg_mean;
        out[2] = pnum;
        out[3] = nnum;
        out[4] = pos_mean + neg_mean;
    }
}

extern "C" void kernel_launch(void* const* d_in, const int* in_sizes, int n_in,
                              void* d_out, int out_size, void* d_ws, size_t ws_size,
                              hipStream_t stream) {
    const float* pooled      = (const float*)d_in[0];
    const float* ood         = (const float*)d_in[1];
    const float* cent        = (const float*)d_in[2];
    const float* delta       = (const float*)d_in[3];
    const float* L           = (const float*)d_in[4];
    const float* U           = (const float*)d_in[5];
    const float* Dd          = (const float*)d_in[6];
    const int*   labels      = (const int*)d_in[7];
    const int*   ball_labels = (const int*)d_in[8];
    float* out = (float*)d_out;

    char* base = (char*)d_ws;
    size_t off = 0;
    auto carve = [&](size_t bytes) -> void* {
        off = (off + 255) & ~(size_t)255;
        void* p = base + off;
        off += bytes;
        return p;
    };
    u16*   xsrc      = (u16*)carve((size_t)512 * FEAT * 2);
    u16*   cent_bf   = (u16*)carve((size_t)NBALLS * FEAT * 2);
    float* cnorm     = (float*)carve((size_t)SN * 4);
    float* S         = (float*)carve((size_t)512 * SN * 4);
    int*   cls_cnt   = (int*)carve((size_t)NCLS * 4);
    int*   cls_list  = (int*)carve((size_t)NCLS * 32 * 4);
    int*   ball_ids  = (int*)carve((size_t)BATCH * 4);
    int*   bcount    = (int*)carve((size_t)NCLS * 4);
    int*   blist     = (int*)carve((size_t)NCLS * 64 * 4);
    int*   nearidx   = (int*)carve((size_t)NCLS * BATCH * 4);
    float* euc2_part = (float*)carve((size_t)NCLS * NSLICE * NCOL * 4);
    float* euc2_ood  = (float*)carve((size_t)NCLS * BATCH * 4);
    float* euc2_main = (float*)carve((size_t)BATCH * 4);

    k_prep<<<1037, 256, 0, stream>>>(pooled, ood, cent, ball_labels, xsrc, cent_bf, cnorm,
                                     cls_cnt, cls_list, euc2_main, bcount);
    k_gemm_s<<<dim3(8, 12), 256, 0, stream>>>(xsrc, cent_bf, cnorm, S);
    k_argmin<<<151, 256, 0, stream>>>(S, labels, cls_cnt, cls_list, ball_ids, bcount, blist, nearidx);
    k_gemm2<<<dim3(NSLICE, NCLS), 256, 0, stream>>>(L, U, Dd, xsrc, cent_bf,
                                                    nearidx, bcount, blist, ball_ids, euc2_part);
    k_reduce<<<NCLS, 256, 0, stream>>>(euc2_part, bcount, blist, euc2_ood, euc2_main);
    k_final<<<1, 256, 0, stream>>>(euc2_main, euc2_ood, ball_ids, nearidx, delta, out);
}

// Round 4
// 643.457 us; speedup vs baseline: 1.2739x; 1.2739x over previous
//
#include <hip/hip_runtime.h>

typedef short short8 __attribute__((ext_vector_type(8)));
typedef float floatx16 __attribute__((ext_vector_type(16)));
typedef unsigned short u16;

#define BATCH 256
#define FEAT 768
#define NBALLS 1500
#define NCLS 150
#define NTRI 294528
#define SN 1504          // padded column stride of S
#define NCOL 320         // 256 ood cols + 64 batch slots
#define NSLICE 12        // 12 x 64-row slices of the 768 output rows
#define BETA_C 0.1f

__device__ __forceinline__ u16 f2bf(float f) {
    unsigned u = __float_as_uint(f);
    return (u16)((u + 0x7FFFu + ((u >> 16) & 1u)) >> 16);
}
__device__ __forceinline__ unsigned pack2bf(float lo, float hi) {
    unsigned ul = __float_as_uint(lo); ul = (ul + 0x7FFFu + ((ul >> 16) & 1u)) >> 16;
    unsigned uh = __float_as_uint(hi); uh = (uh + 0x7FFFu + ((uh >> 16) & 1u)) & 0xFFFF0000u;
    return uh | ul;
}
__device__ __forceinline__ unsigned bf16sub2(unsigned a, unsigned b) {
    float lo = __uint_as_float(a << 16) - __uint_as_float(b << 16);
    float hi = __uint_as_float(a & 0xFFFF0000u) - __uint_as_float(b & 0xFFFF0000u);
    unsigned ul = __float_as_uint(lo); ul = (ul + 0x7FFFu + ((ul >> 16) & 1u)) >> 16;
    unsigned uh = __float_as_uint(hi); uh = (uh + 0x7FFFu + ((uh >> 16) & 1u)) & 0xFFFF0000u;
    return uh | ul;
}
__device__ __forceinline__ unsigned trioff(int x) { return ((unsigned)x * (unsigned)(x - 1)) >> 1; }

__device__ __forceinline__ void async_copy16(const u16* g, u16* lds) {
    __builtin_amdgcn_global_load_lds(
        (const __attribute__((address_space(1))) unsigned int*)(g),
        (__attribute__((address_space(3))) unsigned int*)(lds), 16, 0, 0);
}

// ---------------- fused prep: bf16 conversion + centroid norms + class lists + zeroing ----
__global__ __launch_bounds__(256) void k_prep(
    const float* __restrict__ pooled, const float* __restrict__ ood,
    const float* __restrict__ cent, const int* __restrict__ ball_labels,
    u16* __restrict__ xsrc, u16* __restrict__ cent_bf, float* __restrict__ cnorm,
    int* __restrict__ cls_cnt, int* __restrict__ cls_list,
    float* __restrict__ euc2_main, int* __restrict__ bcount) {
    __shared__ int scnt;
    const int t = threadIdx.x, blk = blockIdx.x;
    const int tid = blk * 256 + t, stride = gridDim.x * 256;
    uint2* xp = (uint2*)xsrc;                       // pooled -> rows 0..255
    for (int i = tid; i < (BATCH * FEAT) / 4; i += stride) {
        const float4 v = ((const float4*)pooled)[i];
        xp[i] = make_uint2(pack2bf(v.x, v.y), pack2bf(v.z, v.w));
    }
    uint2* xo = (uint2*)(xsrc + BATCH * FEAT);      // ood -> rows 256..511
    for (int i = tid; i < (BATCH * FEAT) / 4; i += stride) {
        const float4 v = ((const float4*)ood)[i];
        xo[i] = make_uint2(pack2bf(v.x, v.y), pack2bf(v.z, v.w));
    }
    uint2* cd = (uint2*)cent_bf;
    for (int i = tid; i < (NBALLS * FEAT) / 4; i += stride) {
        const float4 v = ((const float4*)cent)[i];
        cd[i] = make_uint2(pack2bf(v.x, v.y), pack2bf(v.z, v.w));
    }
    for (int i = tid; i < BATCH; i += stride) euc2_main[i] = 0.f;
    for (int i = tid; i < NCLS; i += stride) bcount[i] = 0;

    if (blk >= 512 && blk < 512 + 375) {            // centroid squared norms
        int cid = (blk - 512) * 4 + (t >> 6);
        int lane = t & 63;
        const float* row = cent + (size_t)cid * FEAT;
        float s = 0.f;
#pragma unroll
        for (int q = 0; q < FEAT / 64; ++q) { float v = row[lane + q * 64]; s += v * v; }
        for (int o = 32; o > 0; o >>= 1) s += __shfl_down(s, o);
        if (lane == 0) cnorm[cid] = s;
    }
    if (blk >= 887 && blk < 887 + NCLS) {           // per-class ball lists
        int k = blk - 887;
        if (t == 0) scnt = 0;
        __syncthreads();
        for (int n = t; n < NBALLS; n += 256) {
            if (ball_labels[n] == k) {
                int p = atomicAdd(&scnt, 1);
                if (p < 32) cls_list[k * 32 + p] = n;
            }
        }
        __syncthreads();
        if (t == 0) cls_cnt[k] = scnt < 32 ? scnt : 32;
    }
}

// ---------------- S[r][n] = ||c_n||^2 - 2 q_r . c_n (monotone distance surrogate) --------
__global__ __launch_bounds__(256) void k_gemm_s(
    const u16* __restrict__ xsrc, const u16* __restrict__ cent_bf,
    const float* __restrict__ cnorm, float* __restrict__ S) {
    __shared__ u16 Aq[64 * 40];
    __shared__ u16 Bc[128 * 40];
    const int t = threadIdx.x;
    const int r0 = blockIdx.x * 64;
    const int n0 = blockIdx.y * 128;
    const int w = t >> 6, lane = t & 63;
    const int ml = lane & 31, kh = lane >> 5;
    const int rt = w & 1, cg = w >> 1;

    floatx16 acc[2];
#pragma unroll
    for (int ct = 0; ct < 2; ++ct)
#pragma unroll
        for (int e = 0; e < 16; ++e) acc[ct][e] = 0.f;

    const int ar = t >> 2, aj = (t & 3) * 8;
    const u16* asrc = xsrc + (size_t)(r0 + ar) * FEAT;
    const int bcn = t >> 1, bj = (t & 1) * 16;
    const int ng = n0 + bcn;
    const u16* bsrc = cent_bf + (size_t)(ng < NBALLS ? ng : 0) * FEAT;
    const bool bvalid = (ng < NBALLS);

#pragma unroll 1
    for (int k0 = 0; k0 < FEAT; k0 += 32) {
        uint4 av = *(const uint4*)(asrc + k0 + aj);
        uint4 b0, b1;
        if (bvalid) {
            b0 = *(const uint4*)(bsrc + k0 + bj);
            b1 = *(const uint4*)(bsrc + k0 + bj + 8);
        } else { b0 = make_uint4(0,0,0,0); b1 = make_uint4(0,0,0,0); }
        *(uint4*)&Aq[ar * 40 + aj] = av;
        *(uint4*)&Bc[bcn * 40 + bj] = b0;
        *(uint4*)&Bc[bcn * 40 + bj + 8] = b1;
        __syncthreads();
#pragma unroll
        for (int ks = 0; ks < 2; ++ks) {
            short8 a = *(const short8*)&Aq[(rt * 32 + ml) * 40 + ks * 16 + kh * 8];
#pragma unroll
            for (int ct = 0; ct < 2; ++ct) {
                short8 b = *(const short8*)&Bc[((cg * 2 + ct) * 32 + ml) * 40 + ks * 16 + kh * 8];
                acc[ct] = __builtin_amdgcn_mfma_f32_32x32x16_bf16(a, b, acc[ct], 0, 0, 0);
            }
        }
        __syncthreads();
    }
#pragma unroll
    for (int ct = 0; ct < 2; ++ct) {
        int colg = n0 + (cg * 2 + ct) * 32 + ml;
        if (colg >= SN) continue;
        float cn = (colg < NBALLS) ? cnorm[colg] : 0.f;
#pragma unroll
        for (int reg = 0; reg < 16; ++reg) {
            int row = (reg & 3) + 8 * (reg >> 2) + 4 * kh;
            int rgl = r0 + rt * 32 + row;
            S[(size_t)rgl * SN + colg] = cn - 2.f * acc[ct][reg];
        }
    }
}

// ---------------- fused argmins: block 0 = main branch, blocks 1..150 = ood classes ------
__global__ void k_argmin(const float* __restrict__ S, const int* __restrict__ labels,
                         const int* __restrict__ cls_cnt, const int* __restrict__ cls_list,
                         int* __restrict__ ball_ids, int* __restrict__ bcount,
                         int* __restrict__ blist, int* __restrict__ nearidx) {
    const int t = threadIdx.x;
    if (blockIdx.x == 0) {
        int k = labels[t];
        if (k < 0) k = 0; if (k >= NCLS) k = NCLS - 1;
        int cnt = cls_cnt[k];
        float best = 3.4e38f; int bestn = 0;
        for (int i = 0; i < cnt; ++i) {
            int n = cls_list[k * 32 + i];
            float v = S[(size_t)t * SN + n];
            if (v < best) { best = v; bestn = n; }
        }
        ball_ids[t] = bestn;
        int slot = atomicAdd(&bcount[k], 1);
        if (slot < 64) blist[k * 64 + slot] = t;
    } else {
        int k = blockIdx.x - 1;
        int cnt = cls_cnt[k];
        float best = 3.4e38f; int bestn = 0;
        for (int i = 0; i < cnt; ++i) {
            int n = cls_list[k * 32 + i];
            float v = S[(size_t)(BATCH + t) * SN + n];
            if (v < best) { best = v; bestn = n; }
        }
        nearidx[k * BATCH + t] = bestn;
    }
}

// ---------------- X precompute: X[k][col][0..767] bf16 = (o - c) per class/column --------
// grid (150, 10): 32 cols per block, 8 threads per col, 12 uint4 each.
__global__ __launch_bounds__(256) void k_X(
    const u16* __restrict__ xsrc, const u16* __restrict__ cent_bf,
    const int* __restrict__ nearidx, const int* __restrict__ bcount,
    const int* __restrict__ blist, const int* __restrict__ ball_ids,
    u16* __restrict__ X) {
    const int k = blockIdx.x, seg = blockIdx.y, t = threadIdx.x;
    const int col = seg * 32 + (t >> 3);
    const int part = t & 7;
    unsigned oi = 0, ci = 0; bool valid = true;
    if (col < 256) { oi = 256u + col; ci = (unsigned)nearidx[k * BATCH + col]; }
    else {
        int tt = col - 256;
        int bc = bcount[k]; if (bc > 64) bc = 64;
        if (tt < bc) { int b = blist[k * 64 + tt]; oi = (unsigned)b; ci = (unsigned)ball_ids[b]; }
        else valid = false;
    }
    u16* dst = X + ((size_t)k * NCOL + col) * FEAT + part * 8;
    if (!valid) {
        const uint4 z = make_uint4(0u, 0u, 0u, 0u);
#pragma unroll
        for (int q = 0; q < 12; ++q) *(uint4*)(dst + q * 64) = z;
        return;
    }
    const u16* o = xsrc + (size_t)oi * FEAT + part * 8;
    const u16* c = cent_bf + (size_t)ci * FEAT + part * 8;
#pragma unroll
    for (int q = 0; q < 12; ++q) {
        const uint4 ov = *(const uint4*)(o + q * 64);
        const uint4 cv = *(const uint4*)(c + q * 64);
        uint4 rv;
        rv.x = bf16sub2(ov.x, cv.x); rv.y = bf16sub2(ov.y, cv.y);
        rv.z = bf16sub2(ov.z, cv.z); rv.w = bf16sub2(ov.w, cv.w);
        *(uint4*)(dst + q * 64) = rv;
    }
}

// ---------------- THE big kernel: fused R-build + per-class GEMM + column norms ----------
// PRE=true: B from precomputed X via global_load_lds. PRE=false: in-kernel subtract.
// LDS elem (row,k): chunk=k/8,pos=k%8 -> idx = row*64 + ((chunk^(row&7))*8) + pos
template<bool PRE>
__global__ __launch_bounds__(256, 3) void k_gemm2(
    const float* __restrict__ Lp, const float* __restrict__ Up, const float* __restrict__ Ddp,
    const u16* __restrict__ xsrc, const u16* __restrict__ cent_bf, const u16* __restrict__ X,
    const int* __restrict__ nearidx, const int* __restrict__ bcount,
    const int* __restrict__ blist, const int* __restrict__ ball_ids,
    float* __restrict__ euc2_part) {
    __shared__ u16 At[64 * 64];          // 8 KB
    __shared__ u16 Bt[NCOL * 64];        // 40 KB (aliased as sred after the K loop)
    __shared__ unsigned oidx_s[NCOL];
    __shared__ unsigned cidx_s[NCOL];

    const int t = threadIdx.x;
    const int slice = blockIdx.x;
    const int i0 = slice * 64;
    const int k = blockIdx.y;
    const float* __restrict__ Lr = Lp + (size_t)k * NTRI;
    const float* __restrict__ Ur = Up + (size_t)k * NTRI;
    const float* __restrict__ Ddr = Ddp + (size_t)k * FEAT;

    const int w = t >> 6, lane = t & 63;
    const int ml = lane & 31, kh = lane >> 5;
    const int rt = w & 1, cg = w >> 1;

    // A tile: 64 rows x 64 k of R_k -> 16 fp32/thread. Fixed arrays, compile-time buffers.
    auto loadA = [&](int j0, float (&a)[16]) {
        if (j0 + 64 <= i0) {                         // pure lower: rows of L, contiguous
#pragma unroll
            for (int u = 0; u < 2; ++u) {
                const int g = u * 256 + t;
                const float* p = Lr + trioff(i0 + (g >> 3)) + j0 + (g & 7) * 8;
#pragma unroll
                for (int e = 0; e < 8; ++e) a[u * 8 + e] = p[e];
            }
        } else if (j0 >= i0 + 64) {                  // pure upper: columns of U (contig in i)
#pragma unroll
            for (int v = 0; v < 2; ++v) {
                const int jj = (t >> 3) + 32 * v;
                const float* p = Ur + trioff(j0 + jj) + i0 + (t & 7);
#pragma unroll
                for (int e = 0; e < 8; ++e) a[v * 8 + e] = p[8 * e];
            }
        } else {                                     // diagonal tile (j0 == i0)
#pragma unroll
            for (int u = 0; u < 16; ++u) {
                const int idx = u * 256 + t;
                const int i = i0 + (idx >> 6), jg = j0 + (idx & 63);
                float v;
                if (i > jg)      v = Lr[trioff(i) + jg];
                else if (i < jg) v = Ur[trioff(jg) + i];
                else             v = Ddr[i];
                a[u] = v;
            }
        }
    };
    auto storeA = [&](int j0, float (&a)[16]) {
        if (j0 + 64 <= i0) {
#pragma unroll
            for (int u = 0; u < 2; ++u) {
                const int g = u * 256 + t;
                const int row = g >> 3, chunk = g & 7;
                uint4 rv;
                rv.x = pack2bf(a[u*8+0], a[u*8+1]);
                rv.y = pack2bf(a[u*8+2], a[u*8+3]);
                rv.z = pack2bf(a[u*8+4], a[u*8+5]);
                rv.w = pack2bf(a[u*8+6], a[u*8+7]);
                *(uint4*)&At[row * 64 + ((chunk ^ (row & 7)) * 8)] = rv;
            }
        } else if (j0 >= i0 + 64) {
#pragma unroll
            for (int v = 0; v < 2; ++v) {
                const int jj = (t >> 3) + 32 * v;
                const int chunk = jj >> 3, pos = jj & 7;
#pragma unroll
                for (int e = 0; e < 8; ++e) {
                    const int row = (t & 7) + 8 * e;
                    At[row * 64 + ((chunk ^ (row & 7)) * 8) + pos] = f2bf(a[v * 8 + e]);
                }
            }
        } else {
#pragma unroll
            for (int u = 0; u < 16; ++u) {
                const int idx = u * 256 + t;
                const int row = idx >> 6, col = idx & 63;
                At[row * 64 + (((col >> 3) ^ (row & 7)) * 8) + (col & 7)] = f2bf(a[u]);
            }
        }
    };

    // B staging
    const u16* xkb = X + (size_t)k * NCOL * FEAT
                   + ((size_t)w * 80 + (lane >> 3)) * FEAT
                   + ((lane & 7) ^ ((lane >> 3) & 7)) * 8;     // per-lane base (PRE path)
    u16* ldsb = &Bt[(w * 10) * 512 + (lane ? 0 : 0)];          // wave-uniform base
    auto issueB = [&](int j0) {
#pragma unroll
        for (int u = 0; u < 10; ++u)
            async_copy16(xkb + (size_t)u * 8 * FEAT + j0, &Bt[(w * 10 + u) * 512]);
    };
    auto stageB_sub = [&](int j0) {                  // fallback: in-kernel subtract
#pragma unroll
        for (int u = 0; u < 10; ++u) {
            const int g = u * 256 + t;
            const int col = g >> 3, chunk = g & 7;
            const unsigned ci = cidx_s[col];
            u16* dst = &Bt[col * 64 + ((chunk ^ (col & 7)) * 8)];
            if (ci == 0xFFFFFFFFu) {
                *(uint4*)dst = make_uint4(0u, 0u, 0u, 0u);
            } else {
                const u16* o = xsrc + (size_t)oidx_s[col] * FEAT + j0 + chunk * 8;
                const u16* c = cent_bf + (size_t)ci * FEAT + j0 + chunk * 8;
                const uint4 ov = *(const uint4*)o;
                const uint4 cv = *(const uint4*)c;
                uint4 rv;
                rv.x = bf16sub2(ov.x, cv.x); rv.y = bf16sub2(ov.y, cv.y);
                rv.z = bf16sub2(ov.z, cv.z); rv.w = bf16sub2(ov.w, cv.w);
                *(uint4*)dst = rv;
            }
        }
    };

    float aA[16], aB[16];
    loadA(0, aA);

    if constexpr (!PRE) {
        int bc = bcount[k]; if (bc > 64) bc = 64;
        oidx_s[t] = 256u + (unsigned)t;
        cidx_s[t] = (unsigned)nearidx[k * BATCH + t];
        if (t < 64) {
            unsigned oi = 0u, ci = 0xFFFFFFFFu;
            if (t < bc) { int b = blist[k * 64 + t]; oi = (unsigned)b; ci = (unsigned)ball_ids[b]; }
            oidx_s[256 + t] = oi;
            cidx_s[256 + t] = ci;
        }
        __syncthreads();
    }

    floatx16 acc[5];
#pragma unroll
    for (int cc = 0; cc < 5; ++cc)
#pragma unroll
        for (int e = 0; e < 16; ++e) acc[cc][e] = 0.f;

    auto mfma_sec = [&]() {
#pragma unroll
        for (int ks = 0; ks < 4; ++ks) {
            const int ch = ks * 2 + kh;
            const int arow = rt * 32 + ml;
            const short8 af = *(const short8*)&At[arow * 64 + ((ch ^ (arow & 7)) * 8)];
#pragma unroll
            for (int cc = 0; cc < 5; ++cc) {
                const int brow = (cg * 5 + cc) * 32 + ml;
                const short8 bv = *(const short8*)&Bt[brow * 64 + ((ch ^ (brow & 7)) * 8)];
                acc[cc] = __builtin_amdgcn_mfma_f32_32x32x16_bf16(af, bv, acc[cc], 0, 0, 0);
            }
        }
    };
    auto step = [&](int it, float (&cur)[16], float (&nxt)[16]) {
        const int j0 = it * 64;
        storeA(j0, cur);
        if constexpr (PRE) issueB(j0); else stageB_sub(j0);
        __syncthreads();
        if (it + 1 < NSLICE) loadA(j0 + 64, nxt);    // overlaps the MFMA section
        mfma_sec();
        __syncthreads();
    };

#pragma unroll 1
    for (int it = 0; it < NSLICE; it += 2) {
        step(it,     aA, aB);
        step(it + 1, aB, aA);
    }

    // per-column sum of squares over this 64-row slice; combine row-halves via LDS (alias Bt)
    float* sred = (float*)Bt;
#pragma unroll
    for (int cc = 0; cc < 5; ++cc) {
        float s = 0.f;
#pragma unroll
        for (int e = 0; e < 16; ++e) { float v = acc[cc][e]; s += v * v; }
        s += __shfl_xor(s, 32);
        if (kh == 0) sred[rt * NCOL + cg * 160 + cc * 32 + ml] = s;
    }
    __syncthreads();
    float* outp = euc2_part + ((size_t)k * NSLICE + slice) * NCOL;
    outp[t] = sred[t] + sred[NCOL + t];
    if (t < 64) outp[256 + t] = sred[256 + t] + sred[NCOL + 256 + t];
    (void)ldsb;
}

// ---------------- slice reduction: 12 partials -> euc2 ----------------
__global__ void k_reduce(const float* __restrict__ euc2_part, const int* __restrict__ bcount,
                         const int* __restrict__ blist,
                         float* __restrict__ euc2_ood, float* __restrict__ euc2_main) {
    const int k = blockIdx.x, t = threadIdx.x;
    const float* p = euc2_part + (size_t)k * NSLICE * NCOL;
    float s = 0.f;
#pragma unroll
    for (int s12 = 0; s12 < NSLICE; ++s12) s += p[s12 * NCOL + t];
    euc2_ood[k * BATCH + t] = s;
    if (t < 64) {
        int bc = bcount[k]; if (bc > 64) bc = 64;
        if (t < bc) {
            float s2 = 0.f;
#pragma unroll
            for (int s12 = 0; s12 < NSLICE; ++s12) s2 += p[s12 * NCOL + 256 + t];
            euc2_main[blist[k * 64 + t]] = s2;
        }
    }
}

// ---------------- final loss assembly ----------------
__global__ void k_final(const float* __restrict__ euc2_main, const float* __restrict__ euc2_ood,
                        const int* __restrict__ ball_ids, const int* __restrict__ nearidx,
                        const float* __restrict__ delta, float* __restrict__ out) {
    __shared__ float red[256];
    const int t = threadIdx.x;

    float euc = sqrtf(euc2_main[t]);
    float d = delta[ball_ids[t]];
    float pl = (d > euc) ? expf(euc - d) : (euc - d);
    float pn = (euc > d) ? 1.f : 0.f;
    float nn = (euc < d) ? 1.f : 0.f;

    float s = 0.f;
    for (int k = 0; k < NCLS; ++k) {
        int idx = k * BATCH + t;
        float e = sqrtf(euc2_ood[idx]);
        float dn = delta[nearidx[idx]];
        s += (dn > e) ? (dn - e + BETA_C) : (BETA_C * expf(dn - e));
    }

    auto reduce = [&](float v) -> float {
        red[t] = v; __syncthreads();
        for (int o = 128; o > 0; o >>= 1) {
            if (t < o) red[t] += red[t + o];
            __syncthreads();
        }
        float r = red[0]; __syncthreads();
        return r;
    };
    float pos_sum = reduce(pl);
    float pnum    = reduce(pn);
    float nnum    = reduce(nn);
    float neg_sum = reduce(s);
    if (t == 0) {
        float pos_mean = pos_sum / (float)BATCH;
        float neg_mean = neg_sum / (float)BATCH;
        out[0] = pos_mean;
        out[1] = neg_mean;
        out[2] = pnum;
        out[3] = nnum;
        out[4] = pos_mean + neg_mean;
    }
}

extern "C" void kernel_launch(void* const* d_in, const int* in_sizes, int n_in,
                              void* d_out, int out_size, void* d_ws, size_t ws_size,
                              hipStream_t stream) {
    const float* pooled      = (const float*)d_in[0];
    const float* ood         = (const float*)d_in[1];
    const float* cent        = (const float*)d_in[2];
    const float* delta       = (const float*)d_in[3];
    const float* L           = (const float*)d_in[4];
    const float* U           = (const float*)d_in[5];
    const float* Dd          = (const float*)d_in[6];
    const int*   labels      = (const int*)d_in[7];
    const int*   ball_labels = (const int*)d_in[8];
    float* out = (float*)d_out;

    char* base = (char*)d_ws;
    size_t off = 0;
    auto carve = [&](size_t bytes) -> void* {
        off = (off + 255) & ~(size_t)255;
        void* p = base + off;
        off += bytes;
        return p;
    };
    u16*   xsrc      = (u16*)carve((size_t)512 * FEAT * 2);
    u16*   cent_bf   = (u16*)carve((size_t)NBALLS * FEAT * 2);
    float* cnorm     = (float*)carve((size_t)SN * 4);
    float* S         = (float*)carve((size_t)512 * SN * 4);
    int*   cls_cnt   = (int*)carve((size_t)NCLS * 4);
    int*   cls_list  = (int*)carve((size_t)NCLS * 32 * 4);
    int*   ball_ids  = (int*)carve((size_t)BATCH * 4);
    int*   bcount    = (int*)carve((size_t)NCLS * 4);
    int*   blist     = (int*)carve((size_t)NCLS * 64 * 4);
    int*   nearidx   = (int*)carve((size_t)NCLS * BATCH * 4);
    float* euc2_part = (float*)carve((size_t)NCLS * NSLICE * NCOL * 4);
    float* euc2_ood  = (float*)carve((size_t)NCLS * BATCH * 4);
    float* euc2_main = (float*)carve((size_t)BATCH * 4);
    size_t x_bytes   = (size_t)NCLS * NCOL * FEAT * 2;
    size_t x_off     = (off + 255) & ~(size_t)255;
    bool   use_pre   = (x_off + x_bytes) <= ws_size;
    u16*   X         = use_pre ? (u16*)(base + x_off) : nullptr;

    k_prep<<<1037, 256, 0, stream>>>(pooled, ood, cent, ball_labels, xsrc, cent_bf, cnorm,
                                     cls_cnt, cls_list, euc2_main, bcount);
    k_gemm_s<<<dim3(8, 12), 256, 0, stream>>>(xsrc, cent_bf, cnorm, S);
    k_argmin<<<151, 256, 0, stream>>>(S, labels, cls_cnt, cls_list, ball_ids, bcount, blist, nearidx);
    if (use_pre) {
        k_X<<<dim3(NCLS, 10), 256, 0, stream>>>(xsrc, cent_bf, nearidx, bcount, blist, ball_ids, X);
        k_gemm2<true><<<dim3(NSLICE, NCLS), 256, 0, stream>>>(L, U, Dd, xsrc, cent_bf, X,
                                                              nearidx, bcount, blist, ball_ids,
                                                              euc2_part);
    } else {
        k_gemm2<false><<<dim3(NSLICE, NCLS), 256, 0, stream>>>(L, U, Dd, xsrc, cent_bf, nullptr,
                                                               nearidx, bcount, blist, ball_ids,
                                                               euc2_part);
    }
    k_reduce<<<NCLS, 256, 0, stream>>>(euc2_part, bcount, blist, euc2_ood, euc2_main);
    k_final<<<1, 256, 0, stream>>>(euc2_main, euc2_ood, ball_ids, nearidx, delta, out);
}